// Round 8
// baseline (365.691 us; speedup 1.0000x reference)
//
#include <hip/hip_runtime.h>
#include <math.h>

#define SS 512
#define BB 256
#define DIN 202
#define HH 100
#define TT 19

typedef short short8 __attribute__((ext_vector_type(8)));
typedef float f32x4 __attribute__((ext_vector_type(4)));

#define MFMA16(A, B, C) __builtin_amdgcn_mfma_f32_16x16x32_bf16(A, B, C, 0, 0, 0)

__device__ __forceinline__ float rl(float v, int i) {
    return __int_as_float(__builtin_amdgcn_readlane(__float_as_int(v), i));
}
__device__ __forceinline__ float rfl(float v) {
    return __int_as_float(__builtin_amdgcn_readfirstlane(__float_as_int(v)));
}
__device__ __forceinline__ unsigned short f2bf(float f) {
  unsigned u = __float_as_uint(f);
  u += 0x7fff + ((u >> 16) & 1);   // RNE
  return (unsigned short)(u >> 16);
}
__device__ __forceinline__ float bf2f(unsigned v) {
  return __int_as_float((int)(v << 16));
}
__device__ __forceinline__ float fast_tanh(float z) {
  float e = __expf(2.f * z);
  return (e - 1.f) * __fdividef(1.f, e + 1.f);
}
__device__ __forceinline__ void gl_lds16(const void* g, void* l) {
  __builtin_amdgcn_global_load_lds(
      (const __attribute__((address_space(1))) unsigned int*)g,
      (__attribute__((address_space(3))) unsigned int*)l, 16, 0, 0);
}
// v_cvt_pk_bf16_f32: RNE, bit-identical to f2bf (verified R6/R7, absmax 0).
__device__ __forceinline__ unsigned cvt_pk_bf16(float lo, float hi) {
  unsigned r;
  asm("v_cvt_pk_bf16_f32 %0, %1, %2" : "=v"(r) : "v"(lo), "v"(hi));
  return r;
}
__device__ __forceinline__ uint2 pack_tanh_pk(f32x4 a) {
  float h0 = fast_tanh(a[0]), h1 = fast_tanh(a[1]);
  float h2 = fast_tanh(a[2]), h3 = fast_tanh(a[3]);
  uint2 v;
  v.x = cvt_pk_bf16(h0, h1);
  v.y = cvt_pk_bf16(h2, h3);
  return v;
}
__device__ __forceinline__ uint2 pack_raw_pk(f32x4 a) {
  uint2 v;
  v.x = cvt_pk_bf16(a[0], a[1]);
  v.y = cvt_pk_bf16(a[2], a[3]);
  return v;
}
__device__ __forceinline__ f32x4 seed_from(const void* base, int off) {
  uint2 s = *(const uint2*)((const char*)base + off);
  return (f32x4){bf2f(s.x & 0xffffu), bf2f(s.x >> 16),
                 bf2f(s.y & 0xffffu), bf2f(s.y >> 16)};
}

// ---------------------------------------------------------------------------
// K0: pack W = [Wf;Wb] (200x202 fp32) into frag-linear bf16 tiles.
// ---------------------------------------------------------------------------
__global__ __launch_bounds__(256) void k_cvtW(
    const float* __restrict__ Wf, const float* __restrict__ Wb,
    unsigned short* __restrict__ Wfrag) {
  int w = blockIdx.x * 256 + threadIdx.x;
  if (w >= 7 * 13 * 64) return;
  int kc = w / (13 * 64);
  int r = w % (13 * 64);
  int ft = r >> 6, l = r & 63;
  int nn = ft * 16 + (l & 15);
  int kb = kc * 32 + (l >> 4) * 8;
  union { unsigned short s[8]; int4 v; } pk;
  #pragma unroll
  for (int e = 0; e < 8; ++e) {
    int k = kb + e;
    float vv = 0.f;
    if (k < DIN) {
      if (nn < 100) vv = Wf[(size_t)nn * DIN + k];
      else if (nn < 200) vv = Wb[(size_t)(nn - 100) * DIN + k];
    }
    pk.s[e] = f2bf(vv);
  }
  *(int4*)&Wfrag[(size_t)w * 8] = pk.v;
}

// ---------------------------------------------------------------------------
// K1 (R8): input projection. Stage A REWRITTEN for coalescing: flat
// float2-granule decomposition — per wave, lanes 0..15 read ONE row's 16
// contiguous float2s (128B contiguous), 4 rows/wave/instruction — replacing
// the old 64-lane scattered 8B pattern (16 rows x 808B stride per 16 lanes).
// Same lA frag-linear layout, cvt_pk pack. Everything else identical.
// ---------------------------------------------------------------------------
__global__ __launch_bounds__(256) void k_inproj(
    const float* __restrict__ x, const unsigned short* __restrict__ Wfrag,
    const float* __restrict__ bihf, const float* __restrict__ bhhf,
    const float* __restrict__ bihb, const float* __restrict__ bhhb,
    unsigned short* __restrict__ xpT0, unsigned short* __restrict__ xpT1) {
  __shared__ __align__(16) char smem_raw[28672];
  __shared__ float lbias[208];
  short* lA = (short*)smem_raw;
  short* lB = (short*)(smem_raw + 8192);
  const int t = threadIdx.x;
  const int m0 = blockIdx.x * 128;
  const int s_idx = m0 >> 8;
  const int bhalf = (m0 >> 7) & 1;
  const int wv = t >> 6, lane = t & 63;
  const int li = lane & 15;

  if (t < 208) {
    float bv = 0.f;
    if (t < 100) bv = bihf[t] + bhhf[t];
    else if (t < 200) bv = bihb[t - 100] + bhhb[t - 100];
    lbias[t] = bv;
  }

  f32x4 acc[2][13];
  #pragma unroll
  for (int mf = 0; mf < 2; ++mf)
    #pragma unroll
    for (int nf = 0; nf < 13; ++nf)
      acc[mf][nf] = (f32x4){0.f, 0.f, 0.f, 0.f};

  for (int kc = 0; kc < 7; ++kc) {
    const int k0 = kc * 32;
    __syncthreads();
    // ---- stage A: coalesced granule staging (2048 float2s, 8/thread) ----
    // granule g: row = g>>4 (0..127), cp = g&15 (col pair). Source addr is
    // 8B-aligned ((m0+row)*808 + k0*4 + cp*8). Dest: lA frag-linear 4B word.
    #pragma unroll
    for (int j = 0; j < 8; ++j) {
      int g = t + 256 * j;
      int row = g >> 4, cp = g & 15;
      int col = k0 + cp * 2;
      unsigned pk2 = 0;
      if (col + 1 < DIN) {   // col is even; covers cols {col,col+1} <= 201
        float2 v = *(const float2*)(x + (size_t)(m0 + row) * DIN + col);
        pk2 = cvt_pk_bf16(v.x, v.y);
      }
      int ft = row >> 4, i = row & 15;
      int kq = cp >> 2, e = (cp & 3) * 2;
      *(unsigned*)&lA[ft * 512 + (kq * 16 + i) * 8 + e] = pk2;
    }
    // ---- stage B: 13 direct global->LDS copies from Wfrag ----
    #pragma unroll
    for (int i = 0; i < 4; ++i) {
      int j = i * 4 + wv;
      if (j < 13)
        gl_lds16(Wfrag + ((size_t)(kc * 13 + j)) * 512, &lB[j * 512]);
    }
    __syncthreads();
    short8 a0 = *(const short8*)&lA[(2 * wv + 0) * 512 + lane * 8];
    short8 a1 = *(const short8*)&lA[(2 * wv + 1) * 512 + lane * 8];
    #pragma unroll
    for (int nf = 0; nf < 13; ++nf) {
      short8 b = *(const short8*)&lB[nf * 512 + lane * 8];
      acc[0][nf] = MFMA16(a0, b, acc[0][nf]);
      acc[1][nf] = MFMA16(a1, b, acc[1][nf]);
    }
  }
  __syncthreads();
  unsigned short* ep = (unsigned short*)smem_raw;  // [128][112]
  float biasv[13];
  #pragma unroll
  for (int nf = 0; nf < 13; ++nf) biasv[nf] = lbias[nf * 16 + li];
  const int r0 = (lane >> 4) * 4;
  #pragma unroll
  for (int d = 0; d < 2; ++d) {
    if (d == 1) __syncthreads();
    #pragma unroll
    for (int mf = 0; mf < 2; ++mf) {
      int lrb = (2 * wv + mf) * 16 + r0;
      #pragma unroll
      for (int nf = 0; nf < 13; ++nf) {
        int col = nf * 16 + li;
        int c = col - 100 * d;
        if (c >= 0 && c < 100) {
          #pragma unroll
          for (int r = 0; r < 4; ++r)
            ep[(lrb + r) * 112 + c] = f2bf(acc[mf][nf][r] + biasv[nf]);
        }
      }
    }
    __syncthreads();
    unsigned short* dst0 = d ? xpT1 : xpT0;
    #pragma unroll
    for (int it = 0; it < 7; ++it) {
      int u = t + 256 * it;
      if (u < 1664) {
        int bgrpL = u / 208;
        int rem = u - bgrpL * 208;
        int u8 = rem >> 4, nn = rem & 15;
        int lr = bgrpL * 16 + nn;
        int4 v = *(const int4*)&ep[lr * 112 + u8 * 8];
        size_t off = ((((size_t)s_idx * 16 + bhalf * 8 + bgrpL) * 13 + u8) * 16 + nn) * 8;
        *(int4*)(dst0 + off) = v;
      }
    }
  }
}

// ---------------------------------------------------------------------------
// K2 (R8 = R3 revert + cvt_pk): BALANCED 9-WAVE all-LDS MFMA RNN scan —
// the proven best (79.6us, absmax 0). R7's dual-chain test established that
// step time tracks TOTAL block work/step (36 tiles ~ 830ns; 72 tiles ~
// 1450-1720ns), so amortizing the barrier over more chains is a wash; this
// 96-step / 36-tile-step schedule is the minimum-work configuration at
// warmup=32. cvt_pk packs are bit-identical (R6/R7, absmax 0).
// ---------------------------------------------------------------------------
__global__ __launch_bounds__(576) void k_rnn(
    const unsigned short* __restrict__ xpT0, const unsigned short* __restrict__ xpT1,
    const float* __restrict__ Whf, const float* __restrict__ Whb,
    const float* __restrict__ Wtag, float* __restrict__ plogF, float* __restrict__ plogB) {
  const int bid = blockIdx.x;            // 256 blocks
  const int dir = bid & 1;
  const int bgrp = (bid >> 1) & 15;
  const int b0 = bgrp * 16;
  const int seg = bid >> 5;              // 0..7
  const int start = (seg == 0) ? 0 : (64 * seg - 32);
  const int nch = (64 * seg + 64 - start) >> 3;   // 8 or 12
  const int outbase = 64 * seg;

  const float* Whh = dir ? Whb : Whf;
  const unsigned short* xpX = dir ? xpT1 : xpT0;
  float* plog = dir ? plogB : plogF;

  __shared__ short ringc[9][3][512];          // 27648 B
  __shared__ short ring3[9][128];             //  2304 B
  __shared__ unsigned short xpl[13312];       // 26624 B
  __shared__ unsigned short larc[8 * 16 * 20];// 5120 B
  __shared__ short dummy16[8];

  const int t = threadIdx.x;
  const int wv = t >> 6, lane = t & 63;
  const int n = lane & 15, q = lane >> 4;

  for (int i = t; i < 3 * 512; i += 576) ringc[0][i >> 9][i & 511] = 0;
  for (int i = t; i < 9 * 128; i += 576) ring3[i >> 7][i & 127] = 0;
  if (t < 8) dummy16[t] = 0;

  // ---- one-time A-fragment load: wave wv owns one 16-column block ----
  short8 af[4];
  #pragma unroll
  for (int q2 = 0; q2 < 4; ++q2) af[q2] = (short8){0,0,0,0,0,0,0,0};
  {
    const float* base = nullptr;
    if (wv < 7) {
      int m = 16 * wv + n;
      if (m < HH) base = Whh + (size_t)m * HH;
    } else if (wv == 7) {
      if (n < TT) base = Wtag + (size_t)n * (2 * HH) + dir * HH;
    } else {
      int tA = 16 + n;
      if (tA < TT) base = Wtag + (size_t)tA * (2 * HH) + dir * HH;
    }
    #pragma unroll
    for (int q2 = 0; q2 < 4; ++q2) {
      union { unsigned short s[8]; short8 v; } pa;
      #pragma unroll
      for (int e = 0; e < 8; ++e) {
        int k = 32 * q2 + 8 * q + e;
        pa.s[e] = (base && k < HH) ? f2bf(base[k]) : 0;
      }
      af[q2] = pa.v;
    }
  }

  // mega-load index precompute: 26 units, 9-wave stride
  int slj[3], remj[3];
  #pragma unroll
  for (int i = 0; i < 3; ++i) {
    int j = i * 9 + wv;
    int jj = (j < 26) ? j : 0;
    int unit = jj * 64 + lane;
    slj[i] = unit / 208;
    remj[i] = unit - slj[i] * 208;
  }

  // seed byte-offset within xpl for this wave's 16 columns (wv<7 only)
  const int offW = ((2 * wv + (q >> 1)) * 16 + n) * 16 + (q & 1) * 8;

  for (int cc = 0; cc < nch; ++cc) {
    // ================= mega phase =================
    if (cc > 0) {
      if (t < 128) {
        int sl = t >> 4, nn2 = t & 15;
        int hs = start + (cc - 1) * 8 - 1 + sl;
        if (hs >= outbase) {
          int pos = dir ? (511 - hs) : hs;
          float* dst = plog + ((size_t)pos * 256 + b0 + nn2) * 20;
          const unsigned short* src = &larc[(sl * 16 + nn2) * 20];
          #pragma unroll
          for (int j5 = 0; j5 < 5; ++j5) {
            uint2 rv = *(const uint2*)&src[j5 * 4];
            float4 o;
            o.x = bf2f(rv.x & 0xffffu); o.y = bf2f(rv.x >> 16);
            o.z = bf2f(rv.y & 0xffffu); o.w = bf2f(rv.y >> 16);
            *(float4*)&dst[j5 * 4] = o;
          }
        }
      }
      if (t < 192) {
        *(int4*)&ringc[0][t >> 6][(t & 63) * 8] = *(const int4*)&ringc[8][t >> 6][(t & 63) * 8];
      } else if (t < 208) {
        int i2 = t - 192;
        *(int4*)&ring3[0][i2 * 8] = *(const int4*)&ring3[8][i2 * 8];
      }
    }
    // bulk xp load: contiguous 3328-B runs per (s,bgrp)
    #pragma unroll
    for (int i = 0; i < 3; ++i) {
      int j = i * 9 + wv;
      if (j < 26) {
        int s = start + cc * 8 + slj[i];
        int sq = dir ? (511 - s) : s;
        gl_lds16(xpX + (((size_t)sq * 16 + bgrp) * 208 + remj[i]) * 8, &xpl[j * 512]);
      }
    }
    __syncthreads();   // the only vmcnt-draining barrier per 8 steps

    // ================= 8 inner steps (LDS only) =================
    #pragma unroll
    for (int sl = 0; sl < 8; ++sl) {
      short8 hc0 = *(const short8*)&ringc[sl][0][lane * 8];
      short8 hc1 = *(const short8*)&ringc[sl][1][lane * 8];
      short8 hc2 = *(const short8*)&ringc[sl][2][lane * 8];
      short8 hc3 = *(const short8*)((q == 0) ? &ring3[sl][n * 8] : &dummy16[0]);
      f32x4 z4 = {0.f, 0.f, 0.f, 0.f};
      if (wv < 7) {
        int oW = sl * 3328 + offW;
        if (oW > 26616) oW = 26616;       // wv6 q>=2 pad rows (discarded)
        f32x4 seed = seed_from(xpl, oW);
        f32x4 a0 = MFMA16(af[0], hc0, seed);
        f32x4 a1 = MFMA16(af[1], hc1, z4);
        a0 = MFMA16(af[2], hc2, a0);
        a1 = MFMA16(af[3], hc3, a1);
        f32x4 a = a0 + a1;
        uint2 val = pack_tanh_pk(a);
        if (wv < 6) {
          *(uint2*)&ringc[sl + 1][wv >> 1][((2 * (wv & 1) + (q >> 1)) * 16 + n) * 8 + 4 * (q & 1)] = val;
        } else if (q == 0) {
          *(uint2*)&ring3[sl + 1][n * 8] = val;
        }
      } else {
        f32x4 a0 = MFMA16(af[0], hc0, z4);
        f32x4 a1 = MFMA16(af[1], hc1, z4);
        a0 = MFMA16(af[2], hc2, a0);
        a1 = MFMA16(af[3], hc3, a1);
        f32x4 a = a0 + a1;
        uint2 v = pack_raw_pk(a);
        if (wv == 7) {
          *(uint2*)&larc[(sl * 16 + n) * 20 + 4 * q] = v;
        } else if (q == 0) {
          *(uint2*)&larc[(sl * 16 + n) * 20 + 16] = v;
        }
      }
      __syncthreads();
    }
  }
  // final flush of last chunk's archive
  {
    if (t < 128) {
      int sl = t >> 4, nn2 = t & 15;
      int hs = start + (nch - 1) * 8 - 1 + sl;
      if (hs >= outbase) {
        int pos = dir ? (511 - hs) : hs;
        float* dst = plog + ((size_t)pos * 256 + b0 + nn2) * 20;
        const unsigned short* src = &larc[(sl * 16 + nn2) * 20];
        #pragma unroll
        for (int j5 = 0; j5 < 5; ++j5) {
          uint2 rv = *(const uint2*)&src[j5 * 4];
          float4 o;
          o.x = bf2f(rv.x & 0xffffu); o.y = bf2f(rv.x >> 16);
          o.z = bf2f(rv.y & 0xffffu); o.w = bf2f(rv.y >> 16);
          *(float4*)&dst[j5 * 4] = o;
        }
      }
    }
  }
  // logits for the segment's final h (ring slot 8): waves 7 & 8
  if (wv >= 7) {
    short8 hc0 = *(const short8*)&ringc[8][0][lane * 8];
    short8 hc1 = *(const short8*)&ringc[8][1][lane * 8];
    short8 hc2 = *(const short8*)&ringc[8][2][lane * 8];
    short8 hc3 = *(const short8*)((q == 0) ? &ring3[8][n * 8] : &dummy16[0]);
    f32x4 z4 = {0.f, 0.f, 0.f, 0.f};
    f32x4 a0 = MFMA16(af[0], hc0, z4);
    f32x4 a1 = MFMA16(af[1], hc1, z4);
    a0 = MFMA16(af[2], hc2, a0);
    a1 = MFMA16(af[3], hc3, a1);
    f32x4 a = a0 + a1;
    int hs = start + nch * 8 - 1;
    int pos = dir ? (511 - hs) : hs;
    float* dst = plog + ((size_t)pos * 256 + b0 + n) * 20;
    if (wv == 7) {
      #pragma unroll
      for (int r = 0; r < 4; ++r) dst[4 * q + r] = a[r];
    } else if (q == 0) {
      #pragma unroll
      for (int r = 0; r < 4; ++r) dst[16 + r] = a[r];
    }
  }
}

// ---------------------------------------------------------------------------
// K4 (FUSED softmax+CRF): one wave per sequence (n = s index, L = BB).
// ---------------------------------------------------------------------------
__global__ __launch_bounds__(256) void k_crf(
    const float* __restrict__ plogF, const float* __restrict__ plogB,
    const float* __restrict__ btag, const int* __restrict__ y,
    const float* __restrict__ start, const float* __restrict__ endt,
    const float* __restrict__ trans, float* __restrict__ out) {
  __shared__ float ltr[TT * TT];
  __shared__ float ltb[20];
  __shared__ float lem[4][64 * 21];
  const int t = threadIdx.x;
  const int wave = t >> 6, lane = t & 63;
  const int n = blockIdx.x * 4 + wave;
  for (int i = t; i < TT * TT; i += 256) ltr[i] = trans[i];
  if (t < 20) ltb[t] = (t < TT) ? btag[t] : 0.f;
  __syncthreads();
  const int* yn = y + n * BB;
  float Ereg[TT];
  #pragma unroll
  for (int i = 0; i < TT; ++i) Ereg[i] = (lane < TT) ? __expf(ltr[i * TT + lane]) : 0.f;
  float num = 0.f;
  float alpha = -1e30f;
  for (int c = 0; c < 4; ++c) {
    const size_t gbase = ((size_t)n * BB + c * 64) * 20;
    for (int u = lane; u < 1280; u += 64) {
      int row = u / 20, col = u - row * 20;
      lem[wave][row * 21 + col] = plogF[gbase + u] + plogB[gbase + u] + ltb[col];
    }
    {
      float vv[TT];
      float mx = -1e30f;
      #pragma unroll
      for (int j = 0; j < TT; ++j) { vv[j] = lem[wave][lane * 21 + j]; mx = fmaxf(mx, vv[j]); }
      float ssum = 0.f;
      #pragma unroll
      for (int j = 0; j < TT; ++j) { vv[j] = __expf(vv[j] - mx); ssum += vv[j]; }
      float inv = __fdividef(1.f, ssum);
      #pragma unroll
      for (int j = 0; j < TT; ++j) lem[wave][lane * 21 + j] = vv[j] * inv;
    }
    {
      int l = c * 64 + lane;
      int yt = yn[l];
      num += lem[wave][lane * 21 + yt];
      if (l < BB - 1) num += ltr[yt * TT + yn[l + 1]];
    }
    int llstart = 0;
    if (c == 0) {
      alpha = (lane < TT) ? (start[lane] + lem[wave][lane]) : -1e30f;
      llstart = 1;
    }
    for (int ll = llstart; ll < 64; ++ll) {
      float m = rfl(alpha);
      float ea = __expf(alpha - m);
      float s0 = 0.f, s1 = 0.f;
      #pragma unroll
      for (int i = 0; i < TT; i += 2) {
        s0 = fmaf(rl(ea, i), Ereg[i], s0);
        if (i + 1 < TT) s1 = fmaf(rl(ea, i + 1), Ereg[i + 1], s1);
      }
      float ssum = s0 + s1;
      float em_l = (lane < TT) ? lem[wave][ll * 21 + lane] : 0.f;
      alpha = em_l + m + __logf(ssum);
    }
  }
  #pragma unroll
  for (int o = 1; o < 64; o <<= 1) num += __shfl_xor(num, o);
  float av = alpha + ((lane < TT) ? endt[lane] : 0.f);
  float m2 = rfl(av);
  float ex = (lane < TT) ? __expf(av - m2) : 0.f;
  #pragma unroll
  for (int o = 1; o < 64; o <<= 1) ex += __shfl_xor(ex, o);
  if (lane == 0) {
    float denom = m2 + __logf(ex);
    float res = (start[yn[0]] + endt[yn[BB - 1]] + num) - denom;
    atomicAdd(out, res);
  }
}

// ---------------------------------------------------------------------------
extern "C" void kernel_launch(void* const* d_in, const int* in_sizes, int n_in,
                              void* d_out, int out_size, void* d_ws, size_t ws_size,
                              hipStream_t stream) {
  const float* x     = (const float*)d_in[0];
  const int*   y     = (const int*)d_in[1];
  const float* Wihf  = (const float*)d_in[2];
  const float* Whhf  = (const float*)d_in[3];
  const float* bihf  = (const float*)d_in[4];
  const float* bhhf  = (const float*)d_in[5];
  const float* Wihb  = (const float*)d_in[6];
  const float* Whhb  = (const float*)d_in[7];
  const float* bihb  = (const float*)d_in[8];
  const float* bhhb  = (const float*)d_in[9];
  const float* Wtag  = (const float*)d_in[10];
  const float* btag  = (const float*)d_in[11];
  const float* stt   = (const float*)d_in[12];
  const float* endt  = (const float*)d_in[13];
  const float* trans = (const float*)d_in[14];

  char* w = (char*)d_ws;
  unsigned short* Wfrag = (unsigned short*)w;  w += 128 * 1024;
  unsigned short* xpT0  = (unsigned short*)w;  w += (size_t)512 * 16 * 208 * 16;  // 27.3 MB
  unsigned short* xpT1  = (unsigned short*)w;  w += (size_t)512 * 16 * 208 * 16;
  float* plogF = (float*)w;  w += (size_t)131072 * 20 * 4;
  float* plogB = (float*)w;  w += (size_t)131072 * 20 * 4;

  hipMemsetAsync(d_out, 0, sizeof(float) * out_size, stream);

  k_cvtW<<<23, 256, 0, stream>>>(Wihf, Wihb, Wfrag);
  k_inproj<<<1024, 256, 0, stream>>>(x, Wfrag, bihf, bhhf, bihb, bhhb, xpT0, xpT1);
  k_rnn<<<256, 576, 0, stream>>>(xpT0, xpT1, Whhf, Whhb, Wtag, plogF, plogB);
  k_crf<<<128, 256, 0, stream>>>(plogF, plogB, btag, y, stt, endt, trans, (float*)d_out);
}

// Round 9
// 339.232 us; speedup vs baseline: 1.0780x; 1.0780x over previous
//
#include <hip/hip_runtime.h>
#include <math.h>

#define SS 512
#define BB 256
#define DIN 202
#define HH 100
#define TT 19

typedef short short8 __attribute__((ext_vector_type(8)));
typedef float f32x4 __attribute__((ext_vector_type(4)));

#define MFMA16(A, B, C) __builtin_amdgcn_mfma_f32_16x16x32_bf16(A, B, C, 0, 0, 0)

__device__ __forceinline__ float rl(float v, int i) {
    return __int_as_float(__builtin_amdgcn_readlane(__float_as_int(v), i));
}
__device__ __forceinline__ float rfl(float v) {
    return __int_as_float(__builtin_amdgcn_readfirstlane(__float_as_int(v)));
}
__device__ __forceinline__ unsigned short f2bf(float f) {
  unsigned u = __float_as_uint(f);
  u += 0x7fff + ((u >> 16) & 1);   // RNE
  return (unsigned short)(u >> 16);
}
__device__ __forceinline__ float bf2f(unsigned v) {
  return __int_as_float((int)(v << 16));
}
__device__ __forceinline__ float fast_tanh(float z) {
  float e = __expf(2.f * z);
  return (e - 1.f) * __fdividef(1.f, e + 1.f);
}
__device__ __forceinline__ void gl_lds16(const void* g, void* l) {
  __builtin_amdgcn_global_load_lds(
      (const __attribute__((address_space(1))) unsigned int*)g,
      (__attribute__((address_space(3))) unsigned int*)l, 16, 0, 0);
}
// v_cvt_pk_bf16_f32: RNE, bit-identical to f2bf (verified R6/R7/R8, absmax 0).
__device__ __forceinline__ unsigned cvt_pk_bf16(float lo, float hi) {
  unsigned r;
  asm("v_cvt_pk_bf16_f32 %0, %1, %2" : "=v"(r) : "v"(lo), "v"(hi));
  return r;
}
__device__ __forceinline__ uint2 pack_tanh_pk(f32x4 a) {
  float h0 = fast_tanh(a[0]), h1 = fast_tanh(a[1]);
  float h2 = fast_tanh(a[2]), h3 = fast_tanh(a[3]);
  uint2 v;
  v.x = cvt_pk_bf16(h0, h1);
  v.y = cvt_pk_bf16(h2, h3);
  return v;
}
__device__ __forceinline__ uint2 pack_raw_pk(f32x4 a) {
  uint2 v;
  v.x = cvt_pk_bf16(a[0], a[1]);
  v.y = cvt_pk_bf16(a[2], a[3]);
  return v;
}
__device__ __forceinline__ f32x4 seed_from(const void* base, int off) {
  uint2 s = *(const uint2*)((const char*)base + off);
  return (f32x4){bf2f(s.x & 0xffffu), bf2f(s.x >> 16),
                 bf2f(s.y & 0xffffu), bf2f(s.y >> 16)};
}

// ---------------------------------------------------------------------------
// K0: pack W = [Wf;Wb] (200x202 fp32) into frag-linear bf16 tiles.
// ---------------------------------------------------------------------------
__global__ __launch_bounds__(256) void k_cvtW(
    const float* __restrict__ Wf, const float* __restrict__ Wb,
    unsigned short* __restrict__ Wfrag) {
  int w = blockIdx.x * 256 + threadIdx.x;
  if (w >= 7 * 13 * 64) return;
  int kc = w / (13 * 64);
  int r = w % (13 * 64);
  int ft = r >> 6, l = r & 63;
  int nn = ft * 16 + (l & 15);
  int kb = kc * 32 + (l >> 4) * 8;
  union { unsigned short s[8]; int4 v; } pk;
  #pragma unroll
  for (int e = 0; e < 8; ++e) {
    int k = kb + e;
    float vv = 0.f;
    if (k < DIN) {
      if (nn < 100) vv = Wf[(size_t)nn * DIN + k];
      else if (nn < 200) vv = Wb[(size_t)(nn - 100) * DIN + k];
    }
    pk.s[e] = f2bf(vv);
  }
  *(int4*)&Wfrag[(size_t)w * 8] = pk.v;
}

// ---------------------------------------------------------------------------
// K1 (R9): SOFTWARE-PIPELINED input projection. R8 post-mortem: k_inproj is
// 91us with VALUBusy 7% / MfmaUtil 5% / HBM 16% — i.e. a fully-exposed
// per-iteration latency chain (scattered x loads -> full vmcnt drain at
// barrier -> ds_read -> MFMA -> barrier), ~7800cy/iter with ~1.7 blocks/CU.
// Fix (T14 issue-early/write-late + LDS double-buffer): per kc, issue stage-A
// loads(kc+1) into REGISTERS and gl_lds16 B(kc+1) into the alternate buffer
// BEFORE kc's MFMA phase; convert+ds_write AFTER it; one barrier/iter. Load
// latency hides under 26 MFMAs + 15 ds_reads. Stage-A access pattern
// reverted to the proven R0-R7 one (R8's granule rewrite regressed).
// lA/lB double-buffered: 43008B; epilogue reuses first 28672B unchanged.
// ---------------------------------------------------------------------------
__global__ __launch_bounds__(256) void k_inproj(
    const float* __restrict__ x, const unsigned short* __restrict__ Wfrag,
    const float* __restrict__ bihf, const float* __restrict__ bhhf,
    const float* __restrict__ bihb, const float* __restrict__ bhhb,
    unsigned short* __restrict__ xpT0, unsigned short* __restrict__ xpT1) {
  __shared__ __align__(16) char smem_raw[43008];
  __shared__ float lbias[208];
  const int t = threadIdx.x;
  const int m0 = blockIdx.x * 128;
  const int s_idx = m0 >> 8;
  const int bhalf = (m0 >> 7) & 1;
  const int wv = t >> 6, lane = t & 63;
  const int li = lane & 15;

  short* lAb[2] = {(short*)smem_raw, (short*)(smem_raw + 21504)};
  short* lBb[2] = {(short*)(smem_raw + 8192), (short*)(smem_raw + 29696)};

  if (t < 208) {
    float bv = 0.f;
    if (t < 100) bv = bihf[t] + bhhf[t];
    else if (t < 200) bv = bihb[t - 100] + bhhb[t - 100];
    lbias[t] = bv;
  }

  f32x4 acc[2][13];
  #pragma unroll
  for (int mf = 0; mf < 2; ++mf)
    #pragma unroll
    for (int nf = 0; nf < 13; ++nf)
      acc[mf][nf] = (f32x4){0.f, 0.f, 0.f, 0.f};

  // per-thread stage-A geometry (constant across kc)
  const int u0ft = t >> 6, u0ul = t & 63;
  const int u1ft = (t + 256) >> 6, u1ul = (t + 256) & 63;
  const int rowA[2] = {m0 + u0ft * 16 + (u0ul & 15), m0 + u1ft * 16 + (u1ul & 15)};
  const int kqA[2] = {u0ul >> 4, u1ul >> 4};
  const int dstA[2] = {u0ft * 512 + u0ul * 8, u1ft * 512 + u1ul * 8};

  float2 va[2][4];   // in-flight stage-A values (issue-early, write-late)

  auto issueA = [&](int kc) {
    #pragma unroll
    for (int r = 0; r < 2; ++r) {
      int kbase = kc * 32 + kqA[r] * 8;
      const float* src = x + (size_t)rowA[r] * DIN + kbase;
      if (kbase + 7 < DIN) {
        va[r][0] = *(const float2*)(src);
        va[r][1] = *(const float2*)(src + 2);
        va[r][2] = *(const float2*)(src + 4);
        va[r][3] = *(const float2*)(src + 6);
      } else {
        #pragma unroll
        for (int e2 = 0; e2 < 4; ++e2) {
          float x0 = (kbase + 2 * e2 < DIN) ? src[2 * e2] : 0.f;
          float x1 = (kbase + 2 * e2 + 1 < DIN) ? src[2 * e2 + 1] : 0.f;
          va[r][e2] = make_float2(x0, x1);
        }
      }
    }
  };
  auto writeA = [&](int buf) {
    #pragma unroll
    for (int r = 0; r < 2; ++r) {
      union { unsigned w[4]; int4 v; } pk;
      #pragma unroll
      for (int e2 = 0; e2 < 4; ++e2)
        pk.w[e2] = cvt_pk_bf16(va[r][e2].x, va[r][e2].y);
      *(int4*)&lAb[buf][dstA[r]] = pk.v;
    }
  };
  auto issueB = [&](int kc, int buf) {
    #pragma unroll
    for (int i2 = 0; i2 < 4; ++i2) {
      int j = i2 * 4 + wv;
      if (j < 13)
        gl_lds16(Wfrag + ((size_t)(kc * 13 + j)) * 512, &lBb[buf][j * 512]);
    }
  };

  // prologue: fill buffer 0
  issueA(0);
  issueB(0, 0);
  writeA(0);
  __syncthreads();

  for (int kc = 0; kc < 7; ++kc) {
    const int cur = kc & 1, nxt = cur ^ 1;
    // issue next tile's loads BEFORE compute (latency hides under MFMAs)
    if (kc < 6) {
      issueA(kc + 1);
      issueB(kc + 1, nxt);
    }
    short8 a0 = *(const short8*)&lAb[cur][(2 * wv + 0) * 512 + lane * 8];
    short8 a1 = *(const short8*)&lAb[cur][(2 * wv + 1) * 512 + lane * 8];
    #pragma unroll
    for (int nf = 0; nf < 13; ++nf) {
      short8 b = *(const short8*)&lBb[cur][nf * 512 + lane * 8];
      acc[0][nf] = MFMA16(a0, b, acc[0][nf]);
      acc[1][nf] = MFMA16(a1, b, acc[1][nf]);
    }
    // convert + write next A-tile AFTER compute
    if (kc < 6) writeA(nxt);
    __syncthreads();
  }

  // ---- epilogue: LDS-staged transpose to xpT layout (unchanged) ----
  unsigned short* ep = (unsigned short*)smem_raw;  // [128][112] = 28672B
  float biasv[13];
  #pragma unroll
  for (int nf = 0; nf < 13; ++nf) biasv[nf] = lbias[nf * 16 + li];
  const int r0 = (lane >> 4) * 4;
  #pragma unroll
  for (int d = 0; d < 2; ++d) {
    if (d == 1) __syncthreads();
    #pragma unroll
    for (int mf = 0; mf < 2; ++mf) {
      int lrb = (2 * wv + mf) * 16 + r0;
      #pragma unroll
      for (int nf = 0; nf < 13; ++nf) {
        int col = nf * 16 + li;
        int c = col - 100 * d;
        if (c >= 0 && c < 100) {
          #pragma unroll
          for (int r = 0; r < 4; ++r)
            ep[(lrb + r) * 112 + c] = f2bf(acc[mf][nf][r] + biasv[nf]);
        }
      }
    }
    __syncthreads();
    unsigned short* dst0 = d ? xpT1 : xpT0;
    #pragma unroll
    for (int it = 0; it < 7; ++it) {
      int u = t + 256 * it;
      if (u < 1664) {
        int bgrpL = u / 208;
        int rem = u - bgrpL * 208;
        int u8 = rem >> 4, nn = rem & 15;
        int lr = bgrpL * 16 + nn;
        int4 v = *(const int4*)&ep[lr * 112 + u8 * 8];
        size_t off = ((((size_t)s_idx * 16 + bhalf * 8 + bgrpL) * 13 + u8) * 16 + nn) * 8;
        *(int4*)(dst0 + off) = v;
      }
    }
  }
}

// ---------------------------------------------------------------------------
// K2 (unchanged from R8 = R3 + cvt_pk): BALANCED 9-WAVE all-LDS MFMA RNN
// scan — proven best (~80us, absmax 0). 96 steps x 36 tiles/step is the
// minimum-work schedule at warmup=32 (R7 established step time tracks total
// block work/step, so chain-packing is a wash).
// ---------------------------------------------------------------------------
__global__ __launch_bounds__(576) void k_rnn(
    const unsigned short* __restrict__ xpT0, const unsigned short* __restrict__ xpT1,
    const float* __restrict__ Whf, const float* __restrict__ Whb,
    const float* __restrict__ Wtag, float* __restrict__ plogF, float* __restrict__ plogB) {
  const int bid = blockIdx.x;            // 256 blocks
  const int dir = bid & 1;
  const int bgrp = (bid >> 1) & 15;
  const int b0 = bgrp * 16;
  const int seg = bid >> 5;              // 0..7
  const int start = (seg == 0) ? 0 : (64 * seg - 32);
  const int nch = (64 * seg + 64 - start) >> 3;   // 8 or 12
  const int outbase = 64 * seg;

  const float* Whh = dir ? Whb : Whf;
  const unsigned short* xpX = dir ? xpT1 : xpT0;
  float* plog = dir ? plogB : plogF;

  __shared__ short ringc[9][3][512];          // 27648 B
  __shared__ short ring3[9][128];             //  2304 B
  __shared__ unsigned short xpl[13312];       // 26624 B
  __shared__ unsigned short larc[8 * 16 * 20];// 5120 B
  __shared__ short dummy16[8];

  const int t = threadIdx.x;
  const int wv = t >> 6, lane = t & 63;
  const int n = lane & 15, q = lane >> 4;

  for (int i = t; i < 3 * 512; i += 576) ringc[0][i >> 9][i & 511] = 0;
  for (int i = t; i < 9 * 128; i += 576) ring3[i >> 7][i & 127] = 0;
  if (t < 8) dummy16[t] = 0;

  // ---- one-time A-fragment load: wave wv owns one 16-column block ----
  short8 af[4];
  #pragma unroll
  for (int q2 = 0; q2 < 4; ++q2) af[q2] = (short8){0,0,0,0,0,0,0,0};
  {
    const float* base = nullptr;
    if (wv < 7) {
      int m = 16 * wv + n;
      if (m < HH) base = Whh + (size_t)m * HH;
    } else if (wv == 7) {
      if (n < TT) base = Wtag + (size_t)n * (2 * HH) + dir * HH;
    } else {
      int tA = 16 + n;
      if (tA < TT) base = Wtag + (size_t)tA * (2 * HH) + dir * HH;
    }
    #pragma unroll
    for (int q2 = 0; q2 < 4; ++q2) {
      union { unsigned short s[8]; short8 v; } pa;
      #pragma unroll
      for (int e = 0; e < 8; ++e) {
        int k = 32 * q2 + 8 * q + e;
        pa.s[e] = (base && k < HH) ? f2bf(base[k]) : 0;
      }
      af[q2] = pa.v;
    }
  }

  // mega-load index precompute: 26 units, 9-wave stride
  int slj[3], remj[3];
  #pragma unroll
  for (int i = 0; i < 3; ++i) {
    int j = i * 9 + wv;
    int jj = (j < 26) ? j : 0;
    int unit = jj * 64 + lane;
    slj[i] = unit / 208;
    remj[i] = unit - slj[i] * 208;
  }

  // seed byte-offset within xpl for this wave's 16 columns (wv<7 only)
  const int offW = ((2 * wv + (q >> 1)) * 16 + n) * 16 + (q & 1) * 8;

  for (int cc = 0; cc < nch; ++cc) {
    // ================= mega phase =================
    if (cc > 0) {
      if (t < 128) {
        int sl = t >> 4, nn2 = t & 15;
        int hs = start + (cc - 1) * 8 - 1 + sl;
        if (hs >= outbase) {
          int pos = dir ? (511 - hs) : hs;
          float* dst = plog + ((size_t)pos * 256 + b0 + nn2) * 20;
          const unsigned short* src = &larc[(sl * 16 + nn2) * 20];
          #pragma unroll
          for (int j5 = 0; j5 < 5; ++j5) {
            uint2 rv = *(const uint2*)&src[j5 * 4];
            float4 o;
            o.x = bf2f(rv.x & 0xffffu); o.y = bf2f(rv.x >> 16);
            o.z = bf2f(rv.y & 0xffffu); o.w = bf2f(rv.y >> 16);
            *(float4*)&dst[j5 * 4] = o;
          }
        }
      }
      if (t < 192) {
        *(int4*)&ringc[0][t >> 6][(t & 63) * 8] = *(const int4*)&ringc[8][t >> 6][(t & 63) * 8];
      } else if (t < 208) {
        int i2 = t - 192;
        *(int4*)&ring3[0][i2 * 8] = *(const int4*)&ring3[8][i2 * 8];
      }
    }
    // bulk xp load: contiguous 3328-B runs per (s,bgrp)
    #pragma unroll
    for (int i = 0; i < 3; ++i) {
      int j = i * 9 + wv;
      if (j < 26) {
        int s = start + cc * 8 + slj[i];
        int sq = dir ? (511 - s) : s;
        gl_lds16(xpX + (((size_t)sq * 16 + bgrp) * 208 + remj[i]) * 8, &xpl[j * 512]);
      }
    }
    __syncthreads();   // the only vmcnt-draining barrier per 8 steps

    // ================= 8 inner steps (LDS only) =================
    #pragma unroll
    for (int sl = 0; sl < 8; ++sl) {
      short8 hc0 = *(const short8*)&ringc[sl][0][lane * 8];
      short8 hc1 = *(const short8*)&ringc[sl][1][lane * 8];
      short8 hc2 = *(const short8*)&ringc[sl][2][lane * 8];
      short8 hc3 = *(const short8*)((q == 0) ? &ring3[sl][n * 8] : &dummy16[0]);
      f32x4 z4 = {0.f, 0.f, 0.f, 0.f};
      if (wv < 7) {
        int oW = sl * 3328 + offW;
        if (oW > 26616) oW = 26616;       // wv6 q>=2 pad rows (discarded)
        f32x4 seed = seed_from(xpl, oW);
        f32x4 a0 = MFMA16(af[0], hc0, seed);
        f32x4 a1 = MFMA16(af[1], hc1, z4);
        a0 = MFMA16(af[2], hc2, a0);
        a1 = MFMA16(af[3], hc3, a1);
        f32x4 a = a0 + a1;
        uint2 val = pack_tanh_pk(a);
        if (wv < 6) {
          *(uint2*)&ringc[sl + 1][wv >> 1][((2 * (wv & 1) + (q >> 1)) * 16 + n) * 8 + 4 * (q & 1)] = val;
        } else if (q == 0) {
          *(uint2*)&ring3[sl + 1][n * 8] = val;
        }
      } else {
        f32x4 a0 = MFMA16(af[0], hc0, z4);
        f32x4 a1 = MFMA16(af[1], hc1, z4);
        a0 = MFMA16(af[2], hc2, a0);
        a1 = MFMA16(af[3], hc3, a1);
        f32x4 a = a0 + a1;
        uint2 v = pack_raw_pk(a);
        if (wv == 7) {
          *(uint2*)&larc[(sl * 16 + n) * 20 + 4 * q] = v;
        } else if (q == 0) {
          *(uint2*)&larc[(sl * 16 + n) * 20 + 16] = v;
        }
      }
      __syncthreads();
    }
  }
  // final flush of last chunk's archive
  {
    if (t < 128) {
      int sl = t >> 4, nn2 = t & 15;
      int hs = start + (nch - 1) * 8 - 1 + sl;
      if (hs >= outbase) {
        int pos = dir ? (511 - hs) : hs;
        float* dst = plog + ((size_t)pos * 256 + b0 + nn2) * 20;
        const unsigned short* src = &larc[(sl * 16 + nn2) * 20];
        #pragma unroll
        for (int j5 = 0; j5 < 5; ++j5) {
          uint2 rv = *(const uint2*)&src[j5 * 4];
          float4 o;
          o.x = bf2f(rv.x & 0xffffu); o.y = bf2f(rv.x >> 16);
          o.z = bf2f(rv.y & 0xffffu); o.w = bf2f(rv.y >> 16);
          *(float4*)&dst[j5 * 4] = o;
        }
      }
    }
  }
  // logits for the segment's final h (ring slot 8): waves 7 & 8
  if (wv >= 7) {
    short8 hc0 = *(const short8*)&ringc[8][0][lane * 8];
    short8 hc1 = *(const short8*)&ringc[8][1][lane * 8];
    short8 hc2 = *(const short8*)&ringc[8][2][lane * 8];
    short8 hc3 = *(const short8*)((q == 0) ? &ring3[8][n * 8] : &dummy16[0]);
    f32x4 z4 = {0.f, 0.f, 0.f, 0.f};
    f32x4 a0 = MFMA16(af[0], hc0, z4);
    f32x4 a1 = MFMA16(af[1], hc1, z4);
    a0 = MFMA16(af[2], hc2, a0);
    a1 = MFMA16(af[3], hc3, a1);
    f32x4 a = a0 + a1;
    int hs = start + nch * 8 - 1;
    int pos = dir ? (511 - hs) : hs;
    float* dst = plog + ((size_t)pos * 256 + b0 + n) * 20;
    if (wv == 7) {
      #pragma unroll
      for (int r = 0; r < 4; ++r) dst[4 * q + r] = a[r];
    } else if (q == 0) {
      #pragma unroll
      for (int r = 0; r < 4; ++r) dst[16 + r] = a[r];
    }
  }
}

// ---------------------------------------------------------------------------
// K4 (FUSED softmax+CRF): one wave per sequence (n = s index, L = BB).
// ---------------------------------------------------------------------------
__global__ __launch_bounds__(256) void k_crf(
    const float* __restrict__ plogF, const float* __restrict__ plogB,
    const float* __restrict__ btag, const int* __restrict__ y,
    const float* __restrict__ start, const float* __restrict__ endt,
    const float* __restrict__ trans, float* __restrict__ out) {
  __shared__ float ltr[TT * TT];
  __shared__ float ltb[20];
  __shared__ float lem[4][64 * 21];
  const int t = threadIdx.x;
  const int wave = t >> 6, lane = t & 63;
  const int n = blockIdx.x * 4 + wave;
  for (int i = t; i < TT * TT; i += 256) ltr[i] = trans[i];
  if (t < 20) ltb[t] = (t < TT) ? btag[t] : 0.f;
  __syncthreads();
  const int* yn = y + n * BB;
  float Ereg[TT];
  #pragma unroll
  for (int i = 0; i < TT; ++i) Ereg[i] = (lane < TT) ? __expf(ltr[i * TT + lane]) : 0.f;
  float num = 0.f;
  float alpha = -1e30f;
  for (int c = 0; c < 4; ++c) {
    const size_t gbase = ((size_t)n * BB + c * 64) * 20;
    for (int u = lane; u < 1280; u += 64) {
      int row = u / 20, col = u - row * 20;
      lem[wave][row * 21 + col] = plogF[gbase + u] + plogB[gbase + u] + ltb[col];
    }
    {
      float vv[TT];
      float mx = -1e30f;
      #pragma unroll
      for (int j = 0; j < TT; ++j) { vv[j] = lem[wave][lane * 21 + j]; mx = fmaxf(mx, vv[j]); }
      float ssum = 0.f;
      #pragma unroll
      for (int j = 0; j < TT; ++j) { vv[j] = __expf(vv[j] - mx); ssum += vv[j]; }
      float inv = __fdividef(1.f, ssum);
      #pragma unroll
      for (int j = 0; j < TT; ++j) lem[wave][lane * 21 + j] = vv[j] * inv;
    }
    {
      int l = c * 64 + lane;
      int yt = yn[l];
      num += lem[wave][lane * 21 + yt];
      if (l < BB - 1) num += ltr[yt * TT + yn[l + 1]];
    }
    int llstart = 0;
    if (c == 0) {
      alpha = (lane < TT) ? (start[lane] + lem[wave][lane]) : -1e30f;
      llstart = 1;
    }
    for (int ll = llstart; ll < 64; ++ll) {
      float m = rfl(alpha);
      float ea = __expf(alpha - m);
      float s0 = 0.f, s1 = 0.f;
      #pragma unroll
      for (int i = 0; i < TT; i += 2) {
        s0 = fmaf(rl(ea, i), Ereg[i], s0);
        if (i + 1 < TT) s1 = fmaf(rl(ea, i + 1), Ereg[i + 1], s1);
      }
      float ssum = s0 + s1;
      float em_l = (lane < TT) ? lem[wave][ll * 21 + lane] : 0.f;
      alpha = em_l + m + __logf(ssum);
    }
  }
  #pragma unroll
  for (int o = 1; o < 64; o <<= 1) num += __shfl_xor(num, o);
  float av = alpha + ((lane < TT) ? endt[lane] : 0.f);
  float m2 = rfl(av);
  float ex = (lane < TT) ? __expf(av - m2) : 0.f;
  #pragma unroll
  for (int o = 1; o < 64; o <<= 1) ex += __shfl_xor(ex, o);
  if (lane == 0) {
    float denom = m2 + __logf(ex);
    float res = (start[yn[0]] + endt[yn[BB - 1]] + num) - denom;
    atomicAdd(out, res);
  }
}

// ---------------------------------------------------------------------------
extern "C" void kernel_launch(void* const* d_in, const int* in_sizes, int n_in,
                              void* d_out, int out_size, void* d_ws, size_t ws_size,
                              hipStream_t stream) {
  const float* x     = (const float*)d_in[0];
  const int*   y     = (const int*)d_in[1];
  const float* Wihf  = (const float*)d_in[2];
  const float* Whhf  = (const float*)d_in[3];
  const float* bihf  = (const float*)d_in[4];
  const float* bhhf  = (const float*)d_in[5];
  const float* Wihb  = (const float*)d_in[6];
  const float* Whhb  = (const float*)d_in[7];
  const float* bihb  = (const float*)d_in[8];
  const float* bhhb  = (const float*)d_in[9];
  const float* Wtag  = (const float*)d_in[10];
  const float* btag  = (const float*)d_in[11];
  const float* stt   = (const float*)d_in[12];
  const float* endt  = (const float*)d_in[13];
  const float* trans = (const float*)d_in[14];

  char* w = (char*)d_ws;
  unsigned short* Wfrag = (unsigned short*)w;  w += 128 * 1024;
  unsigned short* xpT0  = (unsigned short*)w;  w += (size_t)512 * 16 * 208 * 16;  // 27.3 MB
  unsigned short* xpT1  = (unsigned short*)w;  w += (size_t)512 * 16 * 208 * 16;
  float* plogF = (float*)w;  w += (size_t)131072 * 20 * 4;
  float* plogB = (float*)w;  w += (size_t)131072 * 20 * 4;

  hipMemsetAsync(d_out, 0, sizeof(float) * out_size, stream);

  k_cvtW<<<23, 256, 0, stream>>>(Wihf, Wihb, Wfrag);
  k_inproj<<<1024, 256, 0, stream>>>(x, Wfrag, bihf, bhhf, bihb, bhhb, xpT0, xpT1);
  k_rnn<<<256, 576, 0, stream>>>(xpT0, xpT1, Whhf, Whhb, Wtag, plogF, plogB);
  k_crf<<<128, 256, 0, stream>>>(plogF, plogB, btag, y, stt, endt, trans, (float*)d_out);
}

// Round 11
// 338.389 us; speedup vs baseline: 1.0807x; 1.0025x over previous
//
#include <hip/hip_runtime.h>
#include <math.h>

#define SS 512
#define BB 256
#define DIN 202
#define HH 100
#define TT 19

typedef short short8 __attribute__((ext_vector_type(8)));
typedef float f32x4 __attribute__((ext_vector_type(4)));

#define MFMA16(A, B, C) __builtin_amdgcn_mfma_f32_16x16x32_bf16(A, B, C, 0, 0, 0)

__device__ __forceinline__ float rl(float v, int i) {
    return __int_as_float(__builtin_amdgcn_readlane(__float_as_int(v), i));
}
__device__ __forceinline__ float rfl(float v) {
    return __int_as_float(__builtin_amdgcn_readfirstlane(__float_as_int(v)));
}
__device__ __forceinline__ unsigned short f2bf(float f) {
  unsigned u = __float_as_uint(f);
  u += 0x7fff + ((u >> 16) & 1);   // RNE
  return (unsigned short)(u >> 16);
}
__device__ __forceinline__ float bf2f(unsigned v) {
  return __int_as_float((int)(v << 16));
}
__device__ __forceinline__ float fast_tanh(float z) {
  float e = __expf(2.f * z);
  return (e - 1.f) * __fdividef(1.f, e + 1.f);
}
__device__ __forceinline__ void gl_lds16(const void* g, void* l) {
  __builtin_amdgcn_global_load_lds(
      (const __attribute__((address_space(1))) unsigned int*)g,
      (__attribute__((address_space(3))) unsigned int*)l, 16, 0, 0);
}
// v_cvt_pk_bf16_f32: RNE, bit-identical to f2bf (verified R6-R9, absmax 0).
__device__ __forceinline__ unsigned cvt_pk_bf16(float lo, float hi) {
  unsigned r;
  asm("v_cvt_pk_bf16_f32 %0, %1, %2" : "=v"(r) : "v"(lo), "v"(hi));
  return r;
}
__device__ __forceinline__ uint2 pack_tanh_pk(f32x4 a) {
  float h0 = fast_tanh(a[0]), h1 = fast_tanh(a[1]);
  float h2 = fast_tanh(a[2]), h3 = fast_tanh(a[3]);
  uint2 v;
  v.x = cvt_pk_bf16(h0, h1);
  v.y = cvt_pk_bf16(h2, h3);
  return v;
}
__device__ __forceinline__ uint2 pack_raw_pk(f32x4 a) {
  uint2 v;
  v.x = cvt_pk_bf16(a[0], a[1]);
  v.y = cvt_pk_bf16(a[2], a[3]);
  return v;
}
__device__ __forceinline__ f32x4 seed_from(const void* base, int off) {
  uint2 s = *(const uint2*)((const char*)base + off);
  return (f32x4){bf2f(s.x & 0xffffu), bf2f(s.x >> 16),
                 bf2f(s.y & 0xffffu), bf2f(s.y >> 16)};
}

// ---------------------------------------------------------------------------
// K0: pack W = [Wf;Wb] (200x202 fp32) into frag-linear bf16 tiles.
// ---------------------------------------------------------------------------
__global__ __launch_bounds__(256) void k_cvtW(
    const float* __restrict__ Wf, const float* __restrict__ Wb,
    unsigned short* __restrict__ Wfrag) {
  int w = blockIdx.x * 256 + threadIdx.x;
  if (w >= 7 * 13 * 64) return;
  int kc = w / (13 * 64);
  int r = w % (13 * 64);
  int ft = r >> 6, l = r & 63;
  int nn = ft * 16 + (l & 15);
  int kb = kc * 32 + (l >> 4) * 8;
  union { unsigned short s[8]; int4 v; } pk;
  #pragma unroll
  for (int e = 0; e < 8; ++e) {
    int k = kb + e;
    float vv = 0.f;
    if (k < DIN) {
      if (nn < 100) vv = Wf[(size_t)nn * DIN + k];
      else if (nn < 200) vv = Wb[(size_t)(nn - 100) * DIN + k];
    }
    pk.s[e] = f2bf(vv);
  }
  *(int4*)&Wfrag[(size_t)w * 8] = pk.v;
}

// ---------------------------------------------------------------------------
// K1 (R11 = R10 fixed): DEPTH-2 software-pipelined input projection.
// R10's compile error: pointer ARRAYS into LDS (short* lAb[2] = {...})
// runtime-indexed from lambdas forced hipcc to emit an addrspacecast static
// initializer (unsupported). Fix: byte-offset arithmetic off smem_raw at
// each use (buf*21504 for A, 8192+buf*21504 for B) — no pointer arrays.
// Pipeline logic unchanged from R10: at iter kc, issue A-loads for tile
// kc+2 into reg slot kc&1; write tile kc+1 (issued a FULL iteration ago,
// loads landed) into lA[nxt] BEFORE the MFMA phase; B depth-1 (L2-hot).
// ---------------------------------------------------------------------------
__global__ __launch_bounds__(256) void k_inproj(
    const float* __restrict__ x, const unsigned short* __restrict__ Wfrag,
    const float* __restrict__ bihf, const float* __restrict__ bhhf,
    const float* __restrict__ bihb, const float* __restrict__ bhhb,
    unsigned short* __restrict__ xpT0, unsigned short* __restrict__ xpT1) {
  __shared__ __align__(16) char smem_raw[43008];
  __shared__ float lbias[208];
  const int t = threadIdx.x;
  const int m0 = blockIdx.x * 128;
  const int s_idx = m0 >> 8;
  const int bhalf = (m0 >> 7) & 1;
  const int wv = t >> 6, lane = t & 63;
  const int li = lane & 15;

  if (t < 208) {
    float bv = 0.f;
    if (t < 100) bv = bihf[t] + bhhf[t];
    else if (t < 200) bv = bihb[t - 100] + bhhb[t - 100];
    lbias[t] = bv;
  }

  f32x4 acc[2][13];
  #pragma unroll
  for (int mf = 0; mf < 2; ++mf)
    #pragma unroll
    for (int nf = 0; nf < 13; ++nf)
      acc[mf][nf] = (f32x4){0.f, 0.f, 0.f, 0.f};

  // per-thread stage-A geometry (constant across kc)
  const int u0ft = t >> 6, u0ul = t & 63;
  const int u1ft = (t + 256) >> 6, u1ul = (t + 256) & 63;
  const int rowA[2] = {m0 + u0ft * 16 + (u0ul & 15), m0 + u1ft * 16 + (u1ul & 15)};
  const int kqA[2] = {u0ul >> 4, u1ul >> 4};
  const int dstA[2] = {u0ft * 1024 + u0ul * 16, u1ft * 1024 + u1ul * 16};  // BYTE offsets

  float2 va[2][2][4];   // [slot][r][e2] — depth-2 in-flight stage-A values

  auto issueA = [&](int kc, int slot) {
    #pragma unroll
    for (int r = 0; r < 2; ++r) {
      int kbase = kc * 32 + kqA[r] * 8;
      const float* src = x + (size_t)rowA[r] * DIN + kbase;
      if (kbase + 7 < DIN) {
        va[slot][r][0] = *(const float2*)(src);
        va[slot][r][1] = *(const float2*)(src + 2);
        va[slot][r][2] = *(const float2*)(src + 4);
        va[slot][r][3] = *(const float2*)(src + 6);
      } else {
        #pragma unroll
        for (int e2 = 0; e2 < 4; ++e2) {
          float x0 = (kbase + 2 * e2 < DIN) ? src[2 * e2] : 0.f;
          float x1 = (kbase + 2 * e2 + 1 < DIN) ? src[2 * e2 + 1] : 0.f;
          va[slot][r][e2] = make_float2(x0, x1);
        }
      }
    }
  };
  auto writeA = [&](int slot, int buf) {
    char* base = smem_raw + buf * 21504;
    #pragma unroll
    for (int r = 0; r < 2; ++r) {
      union { unsigned w[4]; int4 v; } pk;
      #pragma unroll
      for (int e2 = 0; e2 < 4; ++e2)
        pk.w[e2] = cvt_pk_bf16(va[slot][r][e2].x, va[slot][r][e2].y);
      *(int4*)(base + dstA[r]) = pk.v;
    }
  };
  auto issueB = [&](int kc, int buf) {
    char* base = smem_raw + 8192 + buf * 21504;
    #pragma unroll
    for (int i2 = 0; i2 < 4; ++i2) {
      int j = i2 * 4 + wv;
      if (j < 13)
        gl_lds16(Wfrag + ((size_t)(kc * 13 + j)) * 512, base + j * 1024);
    }
  };

  // prologue: tiles 0 and 1 in flight; tile 0 -> LDS buf0
  issueA(0, 0);
  issueA(1, 1);
  issueB(0, 0);
  writeA(0, 0);
  __syncthreads();

  for (int kc = 0; kc < 7; ++kc) {
    const int cur = kc & 1, nxt = cur ^ 1;
    // slot kc&1 held tile kc (already in LDS) -> reuse for tile kc+2
    if (kc + 2 <= 6) issueA(kc + 2, kc & 1);
    if (kc < 6) {
      writeA((kc + 1) & 1, nxt);   // tile kc+1: issued a full iter ago, landed
      issueB(kc + 1, nxt);
    }
    const char* curA = smem_raw + cur * 21504;
    const char* curB = smem_raw + 8192 + cur * 21504;
    short8 a0 = *(const short8*)(curA + (2 * wv + 0) * 1024 + lane * 16);
    short8 a1 = *(const short8*)(curA + (2 * wv + 1) * 1024 + lane * 16);
    #pragma unroll
    for (int nf = 0; nf < 13; ++nf) {
      short8 b = *(const short8*)(curB + nf * 1024 + lane * 16);
      acc[0][nf] = MFMA16(a0, b, acc[0][nf]);
      acc[1][nf] = MFMA16(a1, b, acc[1][nf]);
    }
    __syncthreads();
  }

  // ---- epilogue: LDS-staged transpose to xpT layout (unchanged) ----
  unsigned short* ep = (unsigned short*)smem_raw;  // [128][112] = 28672B
  float biasv[13];
  #pragma unroll
  for (int nf = 0; nf < 13; ++nf) biasv[nf] = lbias[nf * 16 + li];
  const int r0 = (lane >> 4) * 4;
  #pragma unroll
  for (int d = 0; d < 2; ++d) {
    if (d == 1) __syncthreads();
    #pragma unroll
    for (int mf = 0; mf < 2; ++mf) {
      int lrb = (2 * wv + mf) * 16 + r0;
      #pragma unroll
      for (int nf = 0; nf < 13; ++nf) {
        int col = nf * 16 + li;
        int c = col - 100 * d;
        if (c >= 0 && c < 100) {
          #pragma unroll
          for (int r = 0; r < 4; ++r)
            ep[(lrb + r) * 112 + c] = f2bf(acc[mf][nf][r] + biasv[nf]);
        }
      }
    }
    __syncthreads();
    unsigned short* dst0 = d ? xpT1 : xpT0;
    #pragma unroll
    for (int it = 0; it < 7; ++it) {
      int u = t + 256 * it;
      if (u < 1664) {
        int bgrpL = u / 208;
        int rem = u - bgrpL * 208;
        int u8 = rem >> 4, nn = rem & 15;
        int lr = bgrpL * 16 + nn;
        int4 v = *(const int4*)&ep[lr * 112 + u8 * 8];
        size_t off = ((((size_t)s_idx * 16 + bhalf * 8 + bgrpL) * 13 + u8) * 16 + nn) * 8;
        *(int4*)(dst0 + off) = v;
      }
    }
  }
}

// ---------------------------------------------------------------------------
// K2 (unchanged from R9 = R3 + cvt_pk): BALANCED 9-WAVE all-LDS MFMA RNN
// scan — proven best (~76.5us, absmax 0). 96 steps x 36 tiles/step is the
// minimum-work schedule at warmup=32 (R7 established step time tracks total
// block work/step, so chain-packing is a wash).
// ---------------------------------------------------------------------------
__global__ __launch_bounds__(576) void k_rnn(
    const unsigned short* __restrict__ xpT0, const unsigned short* __restrict__ xpT1,
    const float* __restrict__ Whf, const float* __restrict__ Whb,
    const float* __restrict__ Wtag, float* __restrict__ plogF, float* __restrict__ plogB) {
  const int bid = blockIdx.x;            // 256 blocks
  const int dir = bid & 1;
  const int bgrp = (bid >> 1) & 15;
  const int b0 = bgrp * 16;
  const int seg = bid >> 5;              // 0..7
  const int start = (seg == 0) ? 0 : (64 * seg - 32);
  const int nch = (64 * seg + 64 - start) >> 3;   // 8 or 12
  const int outbase = 64 * seg;

  const float* Whh = dir ? Whb : Whf;
  const unsigned short* xpX = dir ? xpT1 : xpT0;
  float* plog = dir ? plogB : plogF;

  __shared__ short ringc[9][3][512];          // 27648 B
  __shared__ short ring3[9][128];             //  2304 B
  __shared__ unsigned short xpl[13312];       // 26624 B
  __shared__ unsigned short larc[8 * 16 * 20];// 5120 B
  __shared__ short dummy16[8];

  const int t = threadIdx.x;
  const int wv = t >> 6, lane = t & 63;
  const int n = lane & 15, q = lane >> 4;

  for (int i = t; i < 3 * 512; i += 576) ringc[0][i >> 9][i & 511] = 0;
  for (int i = t; i < 9 * 128; i += 576) ring3[i >> 7][i & 127] = 0;
  if (t < 8) dummy16[t] = 0;

  // ---- one-time A-fragment load: wave wv owns one 16-column block ----
  short8 af[4];
  #pragma unroll
  for (int q2 = 0; q2 < 4; ++q2) af[q2] = (short8){0,0,0,0,0,0,0,0};
  {
    const float* base = nullptr;
    if (wv < 7) {
      int m = 16 * wv + n;
      if (m < HH) base = Whh + (size_t)m * HH;
    } else if (wv == 7) {
      if (n < TT) base = Wtag + (size_t)n * (2 * HH) + dir * HH;
    } else {
      int tA = 16 + n;
      if (tA < TT) base = Wtag + (size_t)tA * (2 * HH) + dir * HH;
    }
    #pragma unroll
    for (int q2 = 0; q2 < 4; ++q2) {
      union { unsigned short s[8]; short8 v; } pa;
      #pragma unroll
      for (int e = 0; e < 8; ++e) {
        int k = 32 * q2 + 8 * q + e;
        pa.s[e] = (base && k < HH) ? f2bf(base[k]) : 0;
      }
      af[q2] = pa.v;
    }
  }

  // mega-load index precompute: 26 units, 9-wave stride
  int slj[3], remj[3];
  #pragma unroll
  for (int i = 0; i < 3; ++i) {
    int j = i * 9 + wv;
    int jj = (j < 26) ? j : 0;
    int unit = jj * 64 + lane;
    slj[i] = unit / 208;
    remj[i] = unit - slj[i] * 208;
  }

  // seed byte-offset within xpl for this wave's 16 columns (wv<7 only)
  const int offW = ((2 * wv + (q >> 1)) * 16 + n) * 16 + (q & 1) * 8;

  for (int cc = 0; cc < nch; ++cc) {
    // ================= mega phase =================
    if (cc > 0) {
      if (t < 128) {
        int sl = t >> 4, nn2 = t & 15;
        int hs = start + (cc - 1) * 8 - 1 + sl;
        if (hs >= outbase) {
          int pos = dir ? (511 - hs) : hs;
          float* dst = plog + ((size_t)pos * 256 + b0 + nn2) * 20;
          const unsigned short* src = &larc[(sl * 16 + nn2) * 20];
          #pragma unroll
          for (int j5 = 0; j5 < 5; ++j5) {
            uint2 rv = *(const uint2*)&src[j5 * 4];
            float4 o;
            o.x = bf2f(rv.x & 0xffffu); o.y = bf2f(rv.x >> 16);
            o.z = bf2f(rv.y & 0xffffu); o.w = bf2f(rv.y >> 16);
            *(float4*)&dst[j5 * 4] = o;
          }
        }
      }
      if (t < 192) {
        *(int4*)&ringc[0][t >> 6][(t & 63) * 8] = *(const int4*)&ringc[8][t >> 6][(t & 63) * 8];
      } else if (t < 208) {
        int i2 = t - 192;
        *(int4*)&ring3[0][i2 * 8] = *(const int4*)&ring3[8][i2 * 8];
      }
    }
    // bulk xp load: contiguous 3328-B runs per (s,bgrp)
    #pragma unroll
    for (int i = 0; i < 3; ++i) {
      int j = i * 9 + wv;
      if (j < 26) {
        int s = start + cc * 8 + slj[i];
        int sq = dir ? (511 - s) : s;
        gl_lds16(xpX + (((size_t)sq * 16 + bgrp) * 208 + remj[i]) * 8, &xpl[j * 512]);
      }
    }
    __syncthreads();   // the only vmcnt-draining barrier per 8 steps

    // ================= 8 inner steps (LDS only) =================
    #pragma unroll
    for (int sl = 0; sl < 8; ++sl) {
      short8 hc0 = *(const short8*)&ringc[sl][0][lane * 8];
      short8 hc1 = *(const short8*)&ringc[sl][1][lane * 8];
      short8 hc2 = *(const short8*)&ringc[sl][2][lane * 8];
      short8 hc3 = *(const short8*)((q == 0) ? &ring3[sl][n * 8] : &dummy16[0]);
      f32x4 z4 = {0.f, 0.f, 0.f, 0.f};
      if (wv < 7) {
        int oW = sl * 3328 + offW;
        if (oW > 26616) oW = 26616;       // wv6 q>=2 pad rows (discarded)
        f32x4 seed = seed_from(xpl, oW);
        f32x4 a0 = MFMA16(af[0], hc0, seed);
        f32x4 a1 = MFMA16(af[1], hc1, z4);
        a0 = MFMA16(af[2], hc2, a0);
        a1 = MFMA16(af[3], hc3, a1);
        f32x4 a = a0 + a1;
        uint2 val = pack_tanh_pk(a);
        if (wv < 6) {
          *(uint2*)&ringc[sl + 1][wv >> 1][((2 * (wv & 1) + (q >> 1)) * 16 + n) * 8 + 4 * (q & 1)] = val;
        } else if (q == 0) {
          *(uint2*)&ring3[sl + 1][n * 8] = val;
        }
      } else {
        f32x4 a0 = MFMA16(af[0], hc0, z4);
        f32x4 a1 = MFMA16(af[1], hc1, z4);
        a0 = MFMA16(af[2], hc2, a0);
        a1 = MFMA16(af[3], hc3, a1);
        f32x4 a = a0 + a1;
        uint2 v = pack_raw_pk(a);
        if (wv == 7) {
          *(uint2*)&larc[(sl * 16 + n) * 20 + 4 * q] = v;
        } else if (q == 0) {
          *(uint2*)&larc[(sl * 16 + n) * 20 + 16] = v;
        }
      }
      __syncthreads();
    }
  }
  // final flush of last chunk's archive
  {
    if (t < 128) {
      int sl = t >> 4, nn2 = t & 15;
      int hs = start + (nch - 1) * 8 - 1 + sl;
      if (hs >= outbase) {
        int pos = dir ? (511 - hs) : hs;
        float* dst = plog + ((size_t)pos * 256 + b0 + nn2) * 20;
        const unsigned short* src = &larc[(sl * 16 + nn2) * 20];
        #pragma unroll
        for (int j5 = 0; j5 < 5; ++j5) {
          uint2 rv = *(const uint2*)&src[j5 * 4];
          float4 o;
          o.x = bf2f(rv.x & 0xffffu); o.y = bf2f(rv.x >> 16);
          o.z = bf2f(rv.y & 0xffffu); o.w = bf2f(rv.y >> 16);
          *(float4*)&dst[j5 * 4] = o;
        }
      }
    }
  }
  // logits for the segment's final h (ring slot 8): waves 7 & 8
  if (wv >= 7) {
    short8 hc0 = *(const short8*)&ringc[8][0][lane * 8];
    short8 hc1 = *(const short8*)&ringc[8][1][lane * 8];
    short8 hc2 = *(const short8*)&ringc[8][2][lane * 8];
    short8 hc3 = *(const short8*)((q == 0) ? &ring3[8][n * 8] : &dummy16[0]);
    f32x4 z4 = {0.f, 0.f, 0.f, 0.f};
    f32x4 a0 = MFMA16(af[0], hc0, z4);
    f32x4 a1 = MFMA16(af[1], hc1, z4);
    a0 = MFMA16(af[2], hc2, a0);
    a1 = MFMA16(af[3], hc3, a1);
    f32x4 a = a0 + a1;
    int hs = start + nch * 8 - 1;
    int pos = dir ? (511 - hs) : hs;
    float* dst = plog + ((size_t)pos * 256 + b0 + n) * 20;
    if (wv == 7) {
      #pragma unroll
      for (int r = 0; r < 4; ++r) dst[4 * q + r] = a[r];
    } else if (q == 0) {
      #pragma unroll
      for (int r = 0; r < 4; ++r) dst[16 + r] = a[r];
    }
  }
}

// ---------------------------------------------------------------------------
// K4 (FUSED softmax+CRF): one wave per sequence (n = s index, L = BB).
// ---------------------------------------------------------------------------
__global__ __launch_bounds__(256) void k_crf(
    const float* __restrict__ plogF, const float* __restrict__ plogB,
    const float* __restrict__ btag, const int* __restrict__ y,
    const float* __restrict__ start, const float* __restrict__ endt,
    const float* __restrict__ trans, float* __restrict__ out) {
  __shared__ float ltr[TT * TT];
  __shared__ float ltb[20];
  __shared__ float lem[4][64 * 21];
  const int t = threadIdx.x;
  const int wave = t >> 6, lane = t & 63;
  const int n = blockIdx.x * 4 + wave;
  for (int i = t; i < TT * TT; i += 256) ltr[i] = trans[i];
  if (t < 20) ltb[t] = (t < TT) ? btag[t] : 0.f;
  __syncthreads();
  const int* yn = y + n * BB;
  float Ereg[TT];
  #pragma unroll
  for (int i = 0; i < TT; ++i) Ereg[i] = (lane < TT) ? __expf(ltr[i * TT + lane]) : 0.f;
  float num = 0.f;
  float alpha = -1e30f;
  for (int c = 0; c < 4; ++c) {
    const size_t gbase = ((size_t)n * BB + c * 64) * 20;
    for (int u = lane; u < 1280; u += 64) {
      int row = u / 20, col = u - row * 20;
      lem[wave][row * 21 + col] = plogF[gbase + u] + plogB[gbase + u] + ltb[col];
    }
    {
      float vv[TT];
      float mx = -1e30f;
      #pragma unroll
      for (int j = 0; j < TT; ++j) { vv[j] = lem[wave][lane * 21 + j]; mx = fmaxf(mx, vv[j]); }
      float ssum = 0.f;
      #pragma unroll
      for (int j = 0; j < TT; ++j) { vv[j] = __expf(vv[j] - mx); ssum += vv[j]; }
      float inv = __fdividef(1.f, ssum);
      #pragma unroll
      for (int j = 0; j < TT; ++j) lem[wave][lane * 21 + j] = vv[j] * inv;
    }
    {
      int l = c * 64 + lane;
      int yt = yn[l];
      num += lem[wave][lane * 21 + yt];
      if (l < BB - 1) num += ltr[yt * TT + yn[l + 1]];
    }
    int llstart = 0;
    if (c == 0) {
      alpha = (lane < TT) ? (start[lane] + lem[wave][lane]) : -1e30f;
      llstart = 1;
    }
    for (int ll = llstart; ll < 64; ++ll) {
      float m = rfl(alpha);
      float ea = __expf(alpha - m);
      float s0 = 0.f, s1 = 0.f;
      #pragma unroll
      for (int i = 0; i < TT; i += 2) {
        s0 = fmaf(rl(ea, i), Ereg[i], s0);
        if (i + 1 < TT) s1 = fmaf(rl(ea, i + 1), Ereg[i + 1], s1);
      }
      float ssum = s0 + s1;
      float em_l = (lane < TT) ? lem[wave][ll * 21 + lane] : 0.f;
      alpha = em_l + m + __logf(ssum);
    }
  }
  #pragma unroll
  for (int o = 1; o < 64; o <<= 1) num += __shfl_xor(num, o);
  float av = alpha + ((lane < TT) ? endt[lane] : 0.f);
  float m2 = rfl(av);
  float ex = (lane < TT) ? __expf(av - m2) : 0.f;
  #pragma unroll
  for (int o = 1; o < 64; o <<= 1) ex += __shfl_xor(ex, o);
  if (lane == 0) {
    float denom = m2 + __logf(ex);
    float res = (start[yn[0]] + endt[yn[BB - 1]] + num) - denom;
    atomicAdd(out, res);
  }
}

// ---------------------------------------------------------------------------
extern "C" void kernel_launch(void* const* d_in, const int* in_sizes, int n_in,
                              void* d_out, int out_size, void* d_ws, size_t ws_size,
                              hipStream_t stream) {
  const float* x     = (const float*)d_in[0];
  const int*   y     = (const int*)d_in[1];
  const float* Wihf  = (const float*)d_in[2];
  const float* Whhf  = (const float*)d_in[3];
  const float* bihf  = (const float*)d_in[4];
  const float* bhhf  = (const float*)d_in[5];
  const float* Wihb  = (const float*)d_in[6];
  const float* Whhb  = (const float*)d_in[7];
  const float* bihb  = (const float*)d_in[8];
  const float* bhhb  = (const float*)d_in[9];
  const float* Wtag  = (const float*)d_in[10];
  const float* btag  = (const float*)d_in[11];
  const float* stt   = (const float*)d_in[12];
  const float* endt  = (const float*)d_in[13];
  const float* trans = (const float*)d_in[14];

  char* w = (char*)d_ws;
  unsigned short* Wfrag = (unsigned short*)w;  w += 128 * 1024;
  unsigned short* xpT0  = (unsigned short*)w;  w += (size_t)512 * 16 * 208 * 16;  // 27.3 MB
  unsigned short* xpT1  = (unsigned short*)w;  w += (size_t)512 * 16 * 208 * 16;
  float* plogF = (float*)w;  w += (size_t)131072 * 20 * 4;
  float* plogB = (float*)w;  w += (size_t)131072 * 20 * 4;

  hipMemsetAsync(d_out, 0, sizeof(float) * out_size, stream);

  k_cvtW<<<23, 256, 0, stream>>>(Wihf, Wihb, Wfrag);
  k_inproj<<<1024, 256, 0, stream>>>(x, Wfrag, bihf, bhhf, bihb, bhhb, xpT0, xpT1);
  k_rnn<<<256, 576, 0, stream>>>(xpT0, xpT1, Whhf, Whhb, Wtag, plogF, plogB);
  k_crf<<<128, 256, 0, stream>>>(plogF, plogB, btag, y, stt, endt, trans, (float*)d_out);
}